// Round 1
// baseline (398.433 us; speedup 1.0000x reference)
//
#include <hip/hip_runtime.h>

typedef __attribute__((ext_vector_type(8))) short short8;
typedef __attribute__((ext_vector_type(4))) float f32x4;
typedef __attribute__((ext_vector_type(4))) unsigned short u16x4;

constexpr int cB = 2, cN = 4096, cE = 256, cH = 8, cHS = 32;

__device__ __forceinline__ unsigned short f2bf(float f) {
    unsigned int u = __builtin_bit_cast(unsigned int, f);
    u = (u + 0x7FFFu + ((u >> 16) & 1u)) >> 16;
    return (unsigned short)u;
}

// ---- f32 -> bf16 convert: node features (2M elems, 4/thread) ----
__global__ __launch_bounds__(256) void cvt_x_kernel(const float* __restrict__ x,
                                                    unsigned short* __restrict__ xb) {
    int t = blockIdx.x * 256 + threadIdx.x;   // 524288 threads exactly
    f32x4 v = *((const f32x4*)x + t);
    u16x4 o = { f2bf(v[0]), f2bf(v[1]), f2bf(v[2]), f2bf(v[3]) };
    *((u16x4*)xb + t) = o;
}

// ---- f32 -> bf16 convert: Wq|Wk|Wv -> Wcb[768][256] ----
__global__ __launch_bounds__(256) void cvt_w_kernel(const float* __restrict__ Wq,
                                                    const float* __restrict__ Wk,
                                                    const float* __restrict__ Wv,
                                                    unsigned short* __restrict__ wcb) {
    int t = blockIdx.x * 256 + threadIdx.x;   // 49152 threads exactly
    int f = t * 4;
    int o = f >> 8, i = f & 255;
    const float* src = (o < 256) ? Wq : (o < 512 ? Wk : Wv);
    f32x4 v = *(const f32x4*)(src + (size_t)(o & 255) * 256 + i);
    u16x4 ov = { f2bf(v[0]), f2bf(v[1]), f2bf(v[2]), f2bf(v[3]) };
    *((u16x4*)wcb + t) = ov;
}

// ---- adjacency (4-byte elems, nonzero == edge) -> bitmask, 64 bits/wave ----
__global__ __launch_bounds__(256) void bitpack_kernel(const int* __restrict__ adj,
                                                      unsigned long long* __restrict__ mask) {
    int lane = threadIdx.x & 63;
    int wave = blockIdx.x * 4 + (threadIdx.x >> 6);
    const int nwaves = 2048 * 4;
    const int nwords = cB * cN * cN / 64;     // 524288
    for (int w = wave; w < nwords; w += nwaves) {
        int v = adj[(size_t)w * 64 + lane];
        unsigned long long bal = __ballot(v != 0);
        if (lane == 0) mask[w] = bal;
    }
}

// ---- QKV projection: C[8192][768] = Xb @ Wcb^T + bias, MFMA 16x16x32 bf16 ----
// Q,K stored [b][h][n][32] bf16; V stored transposed [b][h][32][n] bf16.
__global__ __launch_bounds__(256) void qkv_proj_kernel(const unsigned short* __restrict__ xb,
                                                       const unsigned short* __restrict__ wcb,
                                                       const float* __restrict__ bq,
                                                       const float* __restrict__ bk,
                                                       const float* __restrict__ bv,
                                                       unsigned short* __restrict__ Qb,
                                                       unsigned short* __restrict__ Kb,
                                                       unsigned short* __restrict__ Vt) {
    const int wv = threadIdx.x >> 6, lane = threadIdx.x & 63;
    const int col = lane & 15, grp = lane >> 4;
    const int rowbase = blockIdx.x * 64 + wv * 16;   // 16 rows per wave
    const int colbase = blockIdx.y * 64;             // 64 cols per block
    f32x4 acc[4] = {};
    for (int kk = 0; kk < 8; ++kk) {
        short8 a = *(const short8*)(xb + (size_t)(rowbase + col) * 256 + kk * 32 + grp * 8);
        #pragma unroll
        for (int c = 0; c < 4; ++c) {
            short8 bf = *(const short8*)(wcb + (size_t)(colbase + c * 16 + col) * 256 + kk * 32 + grp * 8);
            acc[c] = __builtin_amdgcn_mfma_f32_16x16x32_bf16(a, bf, acc[c], 0, 0, 0);
        }
    }
    #pragma unroll
    for (int c = 0; c < 4; ++c) {
        const int o = colbase + c * 16 + col;        // lane's output column
        const int sel = o >> 8, oo = o & 255;
        const float bias = (sel == 0 ? bq : sel == 1 ? bk : bv)[oo];
        const int h = oo >> 5, hs = oo & 31;
        const int R0 = rowbase + grp * 4;            // 4 consecutive rows per lane
        const int b = R0 >> 12, n0 = R0 & 4095;
        if (sel < 2) {
            unsigned short* dst = (sel == 0) ? Qb : Kb;
            #pragma unroll
            for (int r = 0; r < 4; ++r)
                dst[(size_t)((b * cH + h) * cN + n0 + r) * cHS + hs] = f2bf(acc[c][r] + bias);
        } else {
            u16x4 pk = { f2bf(acc[c][0] + bias), f2bf(acc[c][1] + bias),
                         f2bf(acc[c][2] + bias), f2bf(acc[c][3] + bias) };
            *(u16x4*)(Vt + (size_t)((b * cH + h) * cHS + hs) * cN + n0) = pk;
        }
    }
}

// ---- Flash attention with bit-masking. One wave per (b, h, 32-query tile). ----
__global__ __launch_bounds__(256) void attn_kernel(const unsigned short* __restrict__ Qb,
                                                   const unsigned short* __restrict__ Kb,
                                                   const unsigned short* __restrict__ Vt,
                                                   const unsigned int* __restrict__ mask32,
                                                   float* __restrict__ out) {
    // per-wave P staging: 2 qs-regions x 16 rows x 40 ushorts (80B row stride ->
    // bank slot 5r mod 8, all distinct for r mod 8 -> <=2-way conflicts = free)
    __shared__ unsigned short p_smem[4][1280];
    const int wv = threadIdx.x >> 6, lane = threadIdx.x & 63;
    const int col = lane & 15, grp = lane >> 4;
    const int task = blockIdx.x * 4 + wv;            // 0..2047
    const int qt = task & 127, h = (task >> 7) & 7, b = task >> 10;
    const int qbase = qt * 32;
    const unsigned short* Qh = Qb + (size_t)(b * cH + h) * cN * cHS;
    const unsigned short* Kh = Kb + (size_t)(b * cH + h) * cN * cHS;
    const unsigned short* Vh = Vt + (size_t)(b * cH + h) * cHS * cN;
    const unsigned int* mrow = mask32 + (size_t)(b * cN + qbase) * 128;
    unsigned short* pb = p_smem[wv];

    short8 aq[2];
    aq[0] = *(const short8*)(Qh + (size_t)(qbase + col) * cHS + grp * 8);
    aq[1] = *(const short8*)(Qh + (size_t)(qbase + 16 + col) * cHS + grp * 8);

    f32x4 acc[2][2] = {};
    float mm[2][4], ll[2][4];
    #pragma unroll
    for (int r = 0; r < 4; ++r) { mm[0][r] = mm[1][r] = -1e30f; ll[0][r] = ll[1][r] = 0.f; }
    const float CE = 1.4426950408889634f * 0.17677669529663687f;  // log2(e)/sqrt(32)
    const f32x4 z4 = {0.f, 0.f, 0.f, 0.f};

    for (int kt = 0; kt < 128; ++kt) {
        const int kbase = kt * 32;
        short8 bk0 = *(const short8*)(Kh + (size_t)(kbase + col) * cHS + grp * 8);
        short8 bk1 = *(const short8*)(Kh + (size_t)(kbase + 16 + col) * cHS + grp * 8);
        short8 bv0 = *(const short8*)(Vh + (size_t)col * cN + kbase + grp * 8);
        short8 bv1 = *(const short8*)(Vh + (size_t)(16 + col) * cN + kbase + grp * 8);

        f32x4 s[2][2];
        s[0][0] = __builtin_amdgcn_mfma_f32_16x16x32_bf16(aq[0], bk0, z4, 0, 0, 0);
        s[0][1] = __builtin_amdgcn_mfma_f32_16x16x32_bf16(aq[0], bk1, z4, 0, 0, 0);
        s[1][0] = __builtin_amdgcn_mfma_f32_16x16x32_bf16(aq[1], bk0, z4, 0, 0, 0);
        s[1][1] = __builtin_amdgcn_mfma_f32_16x16x32_bf16(aq[1], bk1, z4, 0, 0, 0);

        #pragma unroll
        for (int qs = 0; qs < 2; ++qs) {
            #pragma unroll
            for (int r = 0; r < 4; ++r) {
                const int qrow = qs * 16 + grp * 4 + r;   // local query row (D-layout)
                unsigned int w32 = mrow[(size_t)qrow * 128 + kt];
                float v0 = ((w32 >> col) & 1u) ? s[qs][0][r] : -1e30f;
                float v1 = ((w32 >> (16 + col)) & 1u) ? s[qs][1][r] : -1e30f;
                float mx = fmaxf(v0, v1);
                mx = fmaxf(mx, __shfl_xor(mx, 1));
                mx = fmaxf(mx, __shfl_xor(mx, 2));
                mx = fmaxf(mx, __shfl_xor(mx, 4));
                mx = fmaxf(mx, __shfl_xor(mx, 8));
                float mo = mm[qs][r];
                float mn = fmaxf(mo, mx);
                float scale = __builtin_exp2f((mo - mn) * CE);
                float p0 = __builtin_exp2f((v0 - mn) * CE);
                float p1 = __builtin_exp2f((v1 - mn) * CE);
                float ps = p0 + p1;
                ps += __shfl_xor(ps, 1);
                ps += __shfl_xor(ps, 2);
                ps += __shfl_xor(ps, 4);
                ps += __shfl_xor(ps, 8);
                ll[qs][r] = ll[qs][r] * scale + ps;
                mm[qs][r] = mn;
                acc[qs][0][r] *= scale;
                acc[qs][1][r] *= scale;
                const int row = grp * 4 + r;
                pb[qs * 640 + row * 40 + col]      = f2bf(p0);
                pb[qs * 640 + row * 40 + 16 + col] = f2bf(p1);
            }
        }
        #pragma unroll
        for (int qs = 0; qs < 2; ++qs) {
            short8 pa = *(const short8*)(pb + qs * 640 + col * 40 + grp * 8);
            acc[qs][0] = __builtin_amdgcn_mfma_f32_16x16x32_bf16(pa, bv0, acc[qs][0], 0, 0, 0);
            acc[qs][1] = __builtin_amdgcn_mfma_f32_16x16x32_bf16(pa, bv1, acc[qs][1], 0, 0, 0);
        }
    }

    #pragma unroll
    for (int qs = 0; qs < 2; ++qs) {
        #pragma unroll
        for (int r = 0; r < 4; ++r) {
            const int qrow = qbase + qs * 16 + grp * 4 + r;
            float inv = 1.0f / ll[qs][r];
            float* op = out + (size_t)(b * cN + qrow) * cE + h * 32;
            op[col]      = acc[qs][0][r] * inv;
            op[16 + col] = acc[qs][1][r] * inv;
        }
    }
}

extern "C" void kernel_launch(void* const* d_in, const int* in_sizes, int n_in,
                              void* d_out, int out_size, void* d_ws, size_t ws_size,
                              hipStream_t stream) {
    const float* x   = (const float*)d_in[0];
    const int*   adj = (const int*)d_in[1];
    const float* Wq  = (const float*)d_in[2];
    const float* bq  = (const float*)d_in[3];
    const float* Wk  = (const float*)d_in[4];
    const float* bk  = (const float*)d_in[5];
    const float* Wv  = (const float*)d_in[6];
    const float* bv  = (const float*)d_in[7];
    float* out = (float*)d_out;

    char* ws = (char*)d_ws;
    unsigned short* Xb  = (unsigned short*)(ws);                       // 4 MB
    unsigned short* Wcb = (unsigned short*)(ws + (4ull << 20));        // 384 KB
    unsigned short* Qb  = (unsigned short*)(ws + (5ull << 20));        // 4 MB
    unsigned short* Kb  = (unsigned short*)(ws + (9ull << 20));        // 4 MB
    unsigned short* Vt  = (unsigned short*)(ws + (13ull << 20));       // 4 MB
    unsigned long long* mask64 = (unsigned long long*)(ws + (17ull << 20)); // 4 MB

    cvt_x_kernel<<<dim3(2048), dim3(256), 0, stream>>>(x, Xb);
    cvt_w_kernel<<<dim3(192), dim3(256), 0, stream>>>(Wq, Wk, Wv, Wcb);
    bitpack_kernel<<<dim3(2048), dim3(256), 0, stream>>>(adj, mask64);
    qkv_proj_kernel<<<dim3(128, 12), dim3(256), 0, stream>>>(Xb, Wcb, bq, bk, bv, Qb, Kb, Vt);
    attn_kernel<<<dim3(512), dim3(256), 0, stream>>>(Qb, Kb, Vt, (const unsigned int*)mask64, out);
}

// Round 2
// 196.137 us; speedup vs baseline: 2.0314x; 2.0314x over previous
//
#include <hip/hip_runtime.h>

typedef __attribute__((ext_vector_type(8))) short short8;
typedef __attribute__((ext_vector_type(4))) float f32x4;
typedef __attribute__((ext_vector_type(4))) unsigned short u16x4;

constexpr int cB = 2, cN = 4096, cE = 256, cH = 8, cHS = 32;

__device__ __forceinline__ unsigned short f2bf(float f) {
    unsigned int u = __builtin_bit_cast(unsigned int, f);
    u = (u + 0x7FFFu + ((u >> 16) & 1u)) >> 16;
    return (unsigned short)u;
}

__device__ __forceinline__ unsigned int cvt_pk_bf16(float lo, float hi) {
    unsigned int r;
    asm("v_cvt_pk_bf16_f32 %0, %1, %2" : "=v"(r) : "v"(lo), "v"(hi));
    return r;
}

// ---- f32 -> bf16 convert: node features (2M elems, 4/thread) ----
__global__ __launch_bounds__(256) void cvt_x_kernel(const float* __restrict__ x,
                                                    unsigned short* __restrict__ xb) {
    int t = blockIdx.x * 256 + threadIdx.x;   // 524288 threads exactly
    f32x4 v = *((const f32x4*)x + t);
    u16x4 o = { f2bf(v[0]), f2bf(v[1]), f2bf(v[2]), f2bf(v[3]) };
    *((u16x4*)xb + t) = o;
}

// ---- f32 -> bf16 convert: Wq|Wk|Wv -> Wcb[768][256] ----
__global__ __launch_bounds__(256) void cvt_w_kernel(const float* __restrict__ Wq,
                                                    const float* __restrict__ Wk,
                                                    const float* __restrict__ Wv,
                                                    unsigned short* __restrict__ wcb) {
    int t = blockIdx.x * 256 + threadIdx.x;   // 49152 threads exactly
    int f = t * 4;
    int o = f >> 8, i = f & 255;
    const float* src = (o < 256) ? Wq : (o < 512 ? Wk : Wv);
    f32x4 v = *(const f32x4*)(src + (size_t)(o & 255) * 256 + i);
    u16x4 ov = { f2bf(v[0]), f2bf(v[1]), f2bf(v[2]), f2bf(v[3]) };
    *((u16x4*)wcb + t) = ov;
}

// ---- adjacency (4-byte elems, nonzero == edge) -> bitmask, 64 bits/wave ----
__global__ __launch_bounds__(256) void bitpack_kernel(const int* __restrict__ adj,
                                                      unsigned long long* __restrict__ mask) {
    int lane = threadIdx.x & 63;
    int wave = blockIdx.x * 4 + (threadIdx.x >> 6);
    const int nwaves = 2048 * 4;
    const int nwords = cB * cN * cN / 64;     // 524288
    for (int w = wave; w < nwords; w += nwaves) {
        int v = adj[(size_t)w * 64 + lane];
        unsigned long long bal = __ballot(v != 0);
        if (lane == 0) mask[w] = bal;
    }
}

// ---- QKV projection: C[8192][768] = Xb @ Wcb^T + bias, MFMA 16x16x32 bf16 ----
// Q,K stored [b][h][n][32] bf16.
// V stored transposed AND k'-permuted within each 32-block of n:
//   Vt[h][hs][ (n&~31) + 2*(n&15) + ((n>>4)&1) ] = V[n][hs]
// so attn's packed (p_c, p_{16+c}) LDS pairs line up with contiguous V loads.
__global__ __launch_bounds__(256) void qkv_proj_kernel(const unsigned short* __restrict__ xb,
                                                       const unsigned short* __restrict__ wcb,
                                                       const float* __restrict__ bq,
                                                       const float* __restrict__ bk,
                                                       const float* __restrict__ bv,
                                                       unsigned short* __restrict__ Qb,
                                                       unsigned short* __restrict__ Kb,
                                                       unsigned short* __restrict__ Vt) {
    const int wv = threadIdx.x >> 6, lane = threadIdx.x & 63;
    const int col = lane & 15, grp = lane >> 4;
    const int rowbase = blockIdx.x * 64 + wv * 16;   // 16 rows per wave
    const int colbase = blockIdx.y * 64;             // 64 cols per block
    f32x4 acc[4] = {};
    for (int kk = 0; kk < 8; ++kk) {
        short8 a = *(const short8*)(xb + (size_t)(rowbase + col) * 256 + kk * 32 + grp * 8);
        #pragma unroll
        for (int c = 0; c < 4; ++c) {
            short8 bf = *(const short8*)(wcb + (size_t)(colbase + c * 16 + col) * 256 + kk * 32 + grp * 8);
            acc[c] = __builtin_amdgcn_mfma_f32_16x16x32_bf16(a, bf, acc[c], 0, 0, 0);
        }
    }
    #pragma unroll
    for (int c = 0; c < 4; ++c) {
        const int o = colbase + c * 16 + col;        // lane's output column
        const int sel = o >> 8, oo = o & 255;
        const float bias = (sel == 0 ? bq : sel == 1 ? bk : bv)[oo];
        const int h = oo >> 5, hs = oo & 31;
        const int R0 = rowbase + grp * 4;            // 4 consecutive rows per lane
        const int b = R0 >> 12, n0 = R0 & 4095;
        if (sel < 2) {
            unsigned short* dst = (sel == 0) ? Qb : Kb;
            #pragma unroll
            for (int r = 0; r < 4; ++r)
                dst[(size_t)((b * cH + h) * cN + n0 + r) * cHS + hs] = f2bf(acc[c][r] + bias);
        } else {
            unsigned short* vrow = Vt + (size_t)((b * cH + h) * cHS + hs) * cN;
            #pragma unroll
            for (int r = 0; r < 4; ++r) {
                const int n = n0 + r;
                const int pos = (n & ~31) + 2 * (n & 15) + ((n >> 4) & 1);
                vrow[pos] = f2bf(acc[c][r] + bias);
            }
        }
    }
}

// ---- Flash attention, fixed-max softmax (m=0), bit-masking. ----
// One wave per (b, h, 32-query tile); 512 blocks x 4 waves.
__global__ __launch_bounds__(256) void attn_kernel(const unsigned short* __restrict__ Qb,
                                                   const unsigned short* __restrict__ Kb,
                                                   const unsigned short* __restrict__ Vt,
                                                   const unsigned int* __restrict__ mask32,
                                                   float* __restrict__ out) {
    // P staged packed: u32 = (p_c | p_{16+c}<<16) at [qs][row][col], row stride
    // 20 u32 (80B, 16B-aligned reads; writes <=2-way, reads balanced 8/bank).
    __shared__ unsigned int p_smem[4][2][16][20];
    const int wv = threadIdx.x >> 6, lane = threadIdx.x & 63;
    const int col = lane & 15, grp = lane >> 4;
    int bid = blockIdx.x;
    bid = (bid & 7) * 64 + (bid >> 3);               // XCD chunk swizzle (512 = 8*64)
    const int task = bid * 4 + wv;                   // 0..2047
    const int qt = task & 127, h = (task >> 7) & 7, b = task >> 10;
    const int qbase = qt * 32;
    const unsigned short* Qh = Qb + (size_t)(b * cH + h) * cN * cHS;
    const unsigned short* Kh = Kb + (size_t)(b * cH + h) * cN * cHS;
    const unsigned short* Vh = Vt + (size_t)(b * cH + h) * cHS * cN;
    const unsigned int* mrow = mask32 + (size_t)(b * cN + qbase) * 128;
    unsigned int (*pb)[16][20] = p_smem[wv];

    short8 aq[2];
    aq[0] = *(const short8*)(Qh + (size_t)(qbase + col) * cHS + grp * 8);
    aq[1] = *(const short8*)(Qh + (size_t)(qbase + 16 + col) * cHS + grp * 8);

    f32x4 acc[2][2] = {};
    float ll[2][4] = {};                             // per-lane partial row sums
    const float CE = 1.4426950408889634f * 0.17677669529663687f;  // log2(e)/sqrt(32)
    const f32x4 z4 = {0.f, 0.f, 0.f, 0.f};

    // prefetch kt=0
    short8 ck0 = *(const short8*)(Kh + (size_t)col * cHS + grp * 8);
    short8 ck1 = *(const short8*)(Kh + (size_t)(16 + col) * cHS + grp * 8);
    short8 cv0 = *(const short8*)(Vh + (size_t)col * cN + grp * 8);
    short8 cv1 = *(const short8*)(Vh + (size_t)(16 + col) * cN + grp * 8);
    unsigned int cm[8];
    #pragma unroll
    for (int i = 0; i < 8; ++i)
        cm[i] = mrow[(size_t)((i >> 2) * 16 + grp * 4 + (i & 3)) * 128];

    for (int kt = 0; kt < 128; ++kt) {
        const short8 k0 = ck0, k1 = ck1, v0 = cv0, v1 = cv1;
        unsigned int m8[8];
        #pragma unroll
        for (int i = 0; i < 8; ++i) m8[i] = cm[i];
        if (kt < 127) {
            const int kb = (kt + 1) * 32;
            ck0 = *(const short8*)(Kh + (size_t)(kb + col) * cHS + grp * 8);
            ck1 = *(const short8*)(Kh + (size_t)(kb + 16 + col) * cHS + grp * 8);
            cv0 = *(const short8*)(Vh + (size_t)col * cN + kb + grp * 8);
            cv1 = *(const short8*)(Vh + (size_t)(16 + col) * cN + kb + grp * 8);
            #pragma unroll
            for (int i = 0; i < 8; ++i)
                cm[i] = mrow[(size_t)((i >> 2) * 16 + grp * 4 + (i & 3)) * 128 + kt + 1];
        }

        f32x4 s[2][2];
        s[0][0] = __builtin_amdgcn_mfma_f32_16x16x32_bf16(aq[0], k0, z4, 0, 0, 0);
        s[0][1] = __builtin_amdgcn_mfma_f32_16x16x32_bf16(aq[0], k1, z4, 0, 0, 0);
        s[1][0] = __builtin_amdgcn_mfma_f32_16x16x32_bf16(aq[1], k0, z4, 0, 0, 0);
        s[1][1] = __builtin_amdgcn_mfma_f32_16x16x32_bf16(aq[1], k1, z4, 0, 0, 0);

        #pragma unroll
        for (int qs = 0; qs < 2; ++qs) {
            #pragma unroll
            for (int r = 0; r < 4; ++r) {
                const unsigned int w32 = m8[qs * 4 + r];
                float e0 = __builtin_exp2f(s[qs][0][r] * CE);
                float e1 = __builtin_exp2f(s[qs][1][r] * CE);
                e0 = ((w32 >> col) & 1u) ? e0 : 0.f;
                e1 = ((w32 >> (16 + col)) & 1u) ? e1 : 0.f;
                ll[qs][r] += e0 + e1;
                pb[qs][grp * 4 + r][col] = cvt_pk_bf16(e0, e1);
            }
        }
        #pragma unroll
        for (int qs = 0; qs < 2; ++qs) {
            short8 pa = *(const short8*)&pb[qs][col][grp * 4];
            acc[qs][0] = __builtin_amdgcn_mfma_f32_16x16x32_bf16(pa, v0, acc[qs][0], 0, 0, 0);
            acc[qs][1] = __builtin_amdgcn_mfma_f32_16x16x32_bf16(pa, v1, acc[qs][1], 0, 0, 0);
        }
    }

    #pragma unroll
    for (int qs = 0; qs < 2; ++qs) {
        #pragma unroll
        for (int r = 0; r < 4; ++r) {
            float s = ll[qs][r];
            s += __shfl_xor(s, 1);
            s += __shfl_xor(s, 2);
            s += __shfl_xor(s, 4);
            s += __shfl_xor(s, 8);
            const float inv = 1.0f / s;
            const int qrow = qbase + qs * 16 + grp * 4 + r;
            float* op = out + (size_t)(b * cN + qrow) * cE + h * 32;
            op[col]      = acc[qs][0][r] * inv;
            op[16 + col] = acc[qs][1][r] * inv;
        }
    }
}

extern "C" void kernel_launch(void* const* d_in, const int* in_sizes, int n_in,
                              void* d_out, int out_size, void* d_ws, size_t ws_size,
                              hipStream_t stream) {
    const float* x   = (const float*)d_in[0];
    const int*   adj = (const int*)d_in[1];
    const float* Wq  = (const float*)d_in[2];
    const float* bq  = (const float*)d_in[3];
    const float* Wk  = (const float*)d_in[4];
    const float* bk  = (const float*)d_in[5];
    const float* Wv  = (const float*)d_in[6];
    const float* bv  = (const float*)d_in[7];
    float* out = (float*)d_out;

    char* ws = (char*)d_ws;
    unsigned short* Xb  = (unsigned short*)(ws);                       // 4 MB
    unsigned short* Wcb = (unsigned short*)(ws + (4ull << 20));        // 384 KB
    unsigned short* Qb  = (unsigned short*)(ws + (5ull << 20));        // 4 MB
    unsigned short* Kb  = (unsigned short*)(ws + (9ull << 20));        // 4 MB
    unsigned short* Vt  = (unsigned short*)(ws + (13ull << 20));       // 4 MB
    unsigned long long* mask64 = (unsigned long long*)(ws + (17ull << 20)); // 4 MB

    cvt_x_kernel<<<dim3(2048), dim3(256), 0, stream>>>(x, Xb);
    cvt_w_kernel<<<dim3(192), dim3(256), 0, stream>>>(Wq, Wk, Wv, Wcb);
    bitpack_kernel<<<dim3(2048), dim3(256), 0, stream>>>(adj, mask64);
    qkv_proj_kernel<<<dim3(128, 12), dim3(256), 0, stream>>>(Xb, Wcb, bq, bk, bv, Qb, Kb, Vt);
    attn_kernel<<<dim3(512), dim3(256), 0, stream>>>(Qb, Kb, Vt, (const unsigned int*)mask64, out);
}

// Round 3
// 180.877 us; speedup vs baseline: 2.2028x; 1.0844x over previous
//
#include <hip/hip_runtime.h>

typedef __attribute__((ext_vector_type(8))) short short8;
typedef __attribute__((ext_vector_type(4))) float f32x4;
typedef __attribute__((ext_vector_type(4))) unsigned short u16x4;

constexpr int cB = 2, cN = 4096, cE = 256, cH = 8, cHS = 32;

__device__ __forceinline__ unsigned short f2bf(float f) {
    unsigned int u = __builtin_bit_cast(unsigned int, f);
    u = (u + 0x7FFFu + ((u >> 16) & 1u)) >> 16;
    return (unsigned short)u;
}

__device__ __forceinline__ unsigned int cvt_pk_bf16(float lo, float hi) {
    unsigned int r;
    asm("v_cvt_pk_bf16_f32 %0, %1, %2" : "=v"(r) : "v"(lo), "v"(hi));
    return r;
}

// ---- f32 -> bf16 convert: node features (2M elems, 4/thread) ----
__global__ __launch_bounds__(256) void cvt_x_kernel(const float* __restrict__ x,
                                                    unsigned short* __restrict__ xb) {
    int t = blockIdx.x * 256 + threadIdx.x;   // 524288 threads exactly
    f32x4 v = *((const f32x4*)x + t);
    u16x4 o = { f2bf(v[0]), f2bf(v[1]), f2bf(v[2]), f2bf(v[3]) };
    *((u16x4*)xb + t) = o;
}

// ---- f32 -> bf16 convert: Wq|Wk|Wv -> Wcb[768][256] ----
__global__ __launch_bounds__(256) void cvt_w_kernel(const float* __restrict__ Wq,
                                                    const float* __restrict__ Wk,
                                                    const float* __restrict__ Wv,
                                                    unsigned short* __restrict__ wcb) {
    int t = blockIdx.x * 256 + threadIdx.x;   // 49152 threads exactly
    int f = t * 4;
    int o = f >> 8, i = f & 255;
    const float* src = (o < 256) ? Wq : (o < 512 ? Wk : Wv);
    f32x4 v = *(const f32x4*)(src + (size_t)(o & 255) * 256 + i);
    u16x4 ov = { f2bf(v[0]), f2bf(v[1]), f2bf(v[2]), f2bf(v[3]) };
    *((u16x4*)wcb + t) = ov;
}

// ---- adjacency (4-byte elems, nonzero == edge) -> bitmask, 64 bits/wave ----
__global__ __launch_bounds__(256) void bitpack_kernel(const int* __restrict__ adj,
                                                      unsigned long long* __restrict__ mask) {
    int lane = threadIdx.x & 63;
    int wave = blockIdx.x * 4 + (threadIdx.x >> 6);
    const int nwaves = 2048 * 4;
    const int nwords = cB * cN * cN / 64;     // 524288
    for (int w = wave; w < nwords; w += nwaves) {
        int v = adj[(size_t)w * 64 + lane];
        unsigned long long bal = __ballot(v != 0);
        if (lane == 0) mask[w] = bal;
    }
}

// ---- QKV projection: C[8192][768] = Xb @ Wcb^T + bias, MFMA 16x16x32 bf16 ----
// Q stored [b][h][n][32] bf16, PRE-SCALED by log2(e)/sqrt(HS) so attention can
// use exp2 on the raw QK^T output. K stored [b][h][n][32].
// V stored transposed AND k'-permuted within each 32-block of n:
//   Vt[h][hs][ (n&~31) + 2*(n&15) + ((n>>4)&1) ] = V[n][hs]
// so attn's packed (p_c, p_{16+c}) LDS pairs line up with contiguous V loads.
__global__ __launch_bounds__(256) void qkv_proj_kernel(const unsigned short* __restrict__ xb,
                                                       const unsigned short* __restrict__ wcb,
                                                       const float* __restrict__ bq,
                                                       const float* __restrict__ bk,
                                                       const float* __restrict__ bv,
                                                       unsigned short* __restrict__ Qb,
                                                       unsigned short* __restrict__ Kb,
                                                       unsigned short* __restrict__ Vt) {
    const int wv = threadIdx.x >> 6, lane = threadIdx.x & 63;
    const int col = lane & 15, grp = lane >> 4;
    const int rowbase = blockIdx.x * 64 + wv * 16;   // 16 rows per wave
    const int colbase = blockIdx.y * 64;             // 64 cols per block
    const float CE = 1.4426950408889634f * 0.17677669529663687f;  // log2(e)/sqrt(32)
    f32x4 acc[4] = {};
    for (int kk = 0; kk < 8; ++kk) {
        short8 a = *(const short8*)(xb + (size_t)(rowbase + col) * 256 + kk * 32 + grp * 8);
        #pragma unroll
        for (int c = 0; c < 4; ++c) {
            short8 bf = *(const short8*)(wcb + (size_t)(colbase + c * 16 + col) * 256 + kk * 32 + grp * 8);
            acc[c] = __builtin_amdgcn_mfma_f32_16x16x32_bf16(a, bf, acc[c], 0, 0, 0);
        }
    }
    #pragma unroll
    for (int c = 0; c < 4; ++c) {
        const int o = colbase + c * 16 + col;        // lane's output column
        const int sel = o >> 8, oo = o & 255;
        const float bias = (sel == 0 ? bq : sel == 1 ? bk : bv)[oo];
        const int h = oo >> 5, hs = oo & 31;
        const int R0 = rowbase + grp * 4;            // 4 consecutive rows per lane
        const int b = R0 >> 12, n0 = R0 & 4095;
        if (sel == 0) {
            #pragma unroll
            for (int r = 0; r < 4; ++r)
                Qb[(size_t)((b * cH + h) * cN + n0 + r) * cHS + hs] = f2bf((acc[c][r] + bias) * CE);
        } else if (sel == 1) {
            #pragma unroll
            for (int r = 0; r < 4; ++r)
                Kb[(size_t)((b * cH + h) * cN + n0 + r) * cHS + hs] = f2bf(acc[c][r] + bias);
        } else {
            unsigned short* vrow = Vt + (size_t)((b * cH + h) * cHS + hs) * cN;
            #pragma unroll
            for (int r = 0; r < 4; ++r) {
                const int n = n0 + r;
                const int pos = (n & ~31) + 2 * (n & 15) + ((n >> 4) & 1);
                vrow[pos] = f2bf(acc[c][r] + bias);
            }
        }
    }
}

// ---- Flash attention, fixed-max softmax (m=0), bit-masking. ----
// One BLOCK per (b, h, 32-query tile); 4 waves split the key range
// (wave wv handles kt in [wv*32, wv*32+32)). Partials (acc, l) are additive
// under fixed-max softmax; combined through LDS at the end.
__global__ __launch_bounds__(256, 5) void attn_kernel(const unsigned short* __restrict__ Qb,
                                                      const unsigned short* __restrict__ Kb,
                                                      const unsigned short* __restrict__ Vt,
                                                      const unsigned int* __restrict__ mask32,
                                                      float* __restrict__ out) {
    // comb doubles as: per-wave P staging during the loop (first 2560B of each
    // wave's quarter), then [wv][lane][24] f32 partial buffer for the combine.
    __shared__ float comb[4][64][24];
    const int wv = threadIdx.x >> 6, lane = threadIdx.x & 63;
    const int col = lane & 15, grp = lane >> 4;
    int bid = blockIdx.x;
    bid = (bid & 7) * 256 + (bid >> 3);              // XCD chunk swizzle (2048 = 8*256)
    const int qt = bid & 127, h = (bid >> 7) & 7, b = bid >> 10;
    const int qbase = qt * 32;
    const unsigned short* Qh = Qb + (size_t)(b * cH + h) * cN * cHS;
    const unsigned short* Kh = Kb + (size_t)(b * cH + h) * cN * cHS;
    const unsigned short* Vh = Vt + (size_t)(b * cH + h) * cHS * cN;
    const unsigned int* mrow = mask32 + (size_t)(b * cN + qbase) * 128;
    // per-wave P staging area: [qs][16 rows][20 u32], row stride 80B
    unsigned int* pw = (unsigned int*)&comb[0][0][0] + wv * 640;

    const short8 aq0 = *(const short8*)(Qh + (size_t)(qbase + col) * cHS + grp * 8);
    const short8 aq1 = *(const short8*)(Qh + (size_t)(qbase + 16 + col) * cHS + grp * 8);

    f32x4 acc[2][2] = {};
    f32x4 lacc[2] = {};                              // row-sums via ones-MFMA
    const f32x4 z4 = {0.f, 0.f, 0.f, 0.f};
    const short8 ones = { 0x3F80, 0x3F80, 0x3F80, 0x3F80, 0x3F80, 0x3F80, 0x3F80, 0x3F80 };

    const int ktEnd = wv * 32 + 32;
    #pragma unroll 1
    for (int kt = wv * 32; kt < ktEnd; ++kt) {
        const int kbase = kt * 32;
        const short8 k0 = *(const short8*)(Kh + (size_t)(kbase + col) * cHS + grp * 8);
        const short8 k1 = *(const short8*)(Kh + (size_t)(kbase + 16 + col) * cHS + grp * 8);
        const short8 v0 = *(const short8*)(Vh + (size_t)col * cN + kbase + grp * 8);
        const short8 v1 = *(const short8*)(Vh + (size_t)(16 + col) * cN + kbase + grp * 8);

        f32x4 s[2][2];
        s[0][0] = __builtin_amdgcn_mfma_f32_16x16x32_bf16(aq0, k0, z4, 0, 0, 0);
        s[0][1] = __builtin_amdgcn_mfma_f32_16x16x32_bf16(aq0, k1, z4, 0, 0, 0);
        s[1][0] = __builtin_amdgcn_mfma_f32_16x16x32_bf16(aq1, k0, z4, 0, 0, 0);
        s[1][1] = __builtin_amdgcn_mfma_f32_16x16x32_bf16(aq1, k1, z4, 0, 0, 0);

        #pragma unroll
        for (int qs = 0; qs < 2; ++qs) {
            #pragma unroll
            for (int r = 0; r < 4; ++r) {
                const unsigned int w32 = mrow[(size_t)(qs * 16 + grp * 4 + r) * 128 + kt];
                const float e0 = __builtin_exp2f(s[qs][0][r]);
                const float e1 = __builtin_exp2f(s[qs][1][r]);
                const unsigned int msk = ((w32 >> col) & 0x00010001u) * 0xFFFFu;
                pw[qs * 320 + (grp * 4 + r) * 20 + col] = cvt_pk_bf16(e0, e1) & msk;
            }
        }
        #pragma unroll
        for (int qs = 0; qs < 2; ++qs) {
            const short8 pa = *(const short8*)(pw + qs * 320 + col * 20 + grp * 4);
            acc[qs][0] = __builtin_amdgcn_mfma_f32_16x16x32_bf16(pa, v0, acc[qs][0], 0, 0, 0);
            acc[qs][1] = __builtin_amdgcn_mfma_f32_16x16x32_bf16(pa, v1, acc[qs][1], 0, 0, 0);
            lacc[qs]   = __builtin_amdgcn_mfma_f32_16x16x32_bf16(pa, ones, lacc[qs], 0, 0, 0);
        }
    }

    __syncthreads();                                 // all waves done with P areas
    float* me = &comb[wv][lane][0];
    *(f32x4*)(me +  0) = acc[0][0];
    *(f32x4*)(me +  4) = acc[0][1];
    *(f32x4*)(me +  8) = acc[1][0];
    *(f32x4*)(me + 12) = acc[1][1];
    *(f32x4*)(me + 16) = lacc[0];
    *(f32x4*)(me + 20) = lacc[1];
    __syncthreads();

    // combine: thread group sg = wv handles (qs = sg>>1, half = sg&1)
    const int sg = wv, qs = sg >> 1, half = sg & 1;
    const int grp2 = lane >> 4, col2 = lane & 15;
    f32x4 a = {0.f, 0.f, 0.f, 0.f};
    f32x4 l = {0.f, 0.f, 0.f, 0.f};
    #pragma unroll
    for (int w = 0; w < 4; ++w) {
        a += *(const f32x4*)&comb[w][lane][sg * 4];
        l += *(const f32x4*)&comb[w][lane][16 + qs * 4];
    }
    const int row0 = qbase + qs * 16 + grp2 * 4;
    #pragma unroll
    for (int j = 0; j < 4; ++j) {
        out[(size_t)(b * cN + row0 + j) * cE + h * 32 + half * 16 + col2] = a[j] / l[j];
    }
}

extern "C" void kernel_launch(void* const* d_in, const int* in_sizes, int n_in,
                              void* d_out, int out_size, void* d_ws, size_t ws_size,
                              hipStream_t stream) {
    const float* x   = (const float*)d_in[0];
    const int*   adj = (const int*)d_in[1];
    const float* Wq  = (const float*)d_in[2];
    const float* bq  = (const float*)d_in[3];
    const float* Wk  = (const float*)d_in[4];
    const float* bk  = (const float*)d_in[5];
    const float* Wv  = (const float*)d_in[6];
    const float* bv  = (const float*)d_in[7];
    float* out = (float*)d_out;

    char* ws = (char*)d_ws;
    unsigned short* Xb  = (unsigned short*)(ws);                       // 4 MB
    unsigned short* Wcb = (unsigned short*)(ws + (4ull << 20));        // 384 KB
    unsigned short* Qb  = (unsigned short*)(ws + (5ull << 20));        // 4 MB
    unsigned short* Kb  = (unsigned short*)(ws + (9ull << 20));        // 4 MB
    unsigned short* Vt  = (unsigned short*)(ws + (13ull << 20));       // 4 MB
    unsigned long long* mask64 = (unsigned long long*)(ws + (17ull << 20)); // 4 MB

    cvt_x_kernel<<<dim3(2048), dim3(256), 0, stream>>>(x, Xb);
    cvt_w_kernel<<<dim3(192), dim3(256), 0, stream>>>(Wq, Wk, Wv, Wcb);
    bitpack_kernel<<<dim3(2048), dim3(256), 0, stream>>>(adj, mask64);
    qkv_proj_kernel<<<dim3(128, 12), dim3(256), 0, stream>>>(Xb, Wcb, bq, bk, bv, Qb, Kb, Vt);
    attn_kernel<<<dim3(2048), dim3(256), 0, stream>>>(Qb, Kb, Vt, (const unsigned int*)mask64, out);
}